// Round 5
// baseline (1152.853 us; speedup 1.0000x reference)
//
#include <hip/hip_runtime.h>

typedef unsigned short u16;
typedef unsigned int   u32;

__device__ __forceinline__ float bf2f(u16 v) {
  return __uint_as_float(((u32)v) << 16);
}
__device__ __forceinline__ u16 f2bf(float f) {
  u32 u = __float_as_uint(f);
  u32 r = (u + 0x7FFFu + ((u >> 16) & 1u)) >> 16;   // RNE
  return (u16)r;
}
// NaN-propagating ReLU (fmaxf(NaN,0)=0 would hide poison as zeros)
__device__ __forceinline__ float relu(float x) { return x < 0.f ? 0.f : x; }

// ---------------------------------------------------------------------------
// 1. column means of frame batch 0 over c, float64 accumulate, /512 exact.
__global__ void colmeanD_kernel(const float* __restrict__ frame, double* __restrict__ meanD) {
  int tf = blockIdx.x * 256 + threadIdx.x;           // 4096 total
  const float* f0 = frame + tf;
  double s = 0.0;
  for (int c = 0; c < 512; ++c) s += (double)f0[(size_t)c * 4096];
  meanD[tf] = s / 512.0;
}

// ---------------------------------------------------------------------------
// 2. float64: S = sum; q = meanD/S; cumsum; cdf = min(int(c*2048), 2047).
__global__ void scanD_kernel(const double* __restrict__ meanD, int* __restrict__ cdf) {
  __shared__ double part[256];
  __shared__ double base[256];
  __shared__ double Ss;
  int tid = threadIdx.x;
  double loc[16];
  double s = 0.0;
#pragma unroll
  for (int i = 0; i < 16; ++i) { loc[i] = meanD[tid * 16 + i]; s += loc[i]; }
  part[tid] = s;
  __syncthreads();
  if (tid == 0) {
    double t = 0.0;
    for (int i = 0; i < 256; ++i) t += part[i];
    Ss = t;
  }
  __syncthreads();
  double S = Ss;
  s = 0.0;
#pragma unroll
  for (int i = 0; i < 16; ++i) { loc[i] = loc[i] / S; s += loc[i]; }
  part[tid] = s;
  __syncthreads();
  if (tid == 0) {
    double c = 0.0;
    for (int i = 0; i < 256; ++i) { base[i] = c; c += part[i]; }
  }
  __syncthreads();
  double c = base[tid];
#pragma unroll
  for (int i = 0; i < 16; ++i) {
    c += loc[i];
    int iv = (int)(c * 2048.0);                      // trunc = astype(int32)
    cdf[tid * 16 + i] = iv < 2047 ? iv : 2047;
  }
}

// ---------------------------------------------------------------------------
// 3. idx[target] = first argmin_j |cdf[j]-target|   (exact int domain)
__global__ void argmin_kernel(const int* __restrict__ cdf, int* __restrict__ idx) {
  __shared__ int sd[256], sj[256];
  int target = blockIdx.x;                            // 2048 blocks
  int tid = threadIdx.x;
  int best = 0x7fffffff, bj = 0x7fffffff;
  for (int j = tid; j < 4096; j += 256) {
    int d = cdf[j] - target; d = d < 0 ? -d : d;
    if (d < best) { best = d; bj = j; }               // strict < keeps first
  }
  sd[tid] = best; sj[tid] = bj;
  __syncthreads();
  for (int s = 128; s > 0; s >>= 1) {
    if (tid < s) {
      if (sd[tid+s] < sd[tid] || (sd[tid+s] == sd[tid] && sj[tid+s] < sj[tid])) {
        sd[tid] = sd[tid+s]; sj[tid] = sj[tid+s];
      }
    }
    __syncthreads();
  }
  if (tid == 0) idx[target] = sj[0];
}

// ---------------------------------------------------------------------------
// 4. gather: X3[b][c][t] = bf16(frame[b][c][idx[t]]), X3 is (B,2048c,2048t),
//    sampled occupies channel rows 0..511.
__global__ void gather_kernel(const float* __restrict__ frame, const int* __restrict__ idx,
                              u16* __restrict__ X3) {
  int c = blockIdx.x, b = blockIdx.y, tid = threadIdx.x;
  const float* fb = frame + ((size_t)b * 512 + c) * 4096;
  u16* xb = X3 + ((size_t)b * 2048 + c) * 2048;
  for (int t = tid; t < 2048; t += 256) {
    int it = idx[t];
    it = it < 0 ? 0 : (it > 4095 ? 4095 : it);       // defensive clamp
    xb[t] = f2bf(fb[it]);
  }
}

// ---------------------------------------------------------------------------
// 5. fp32 GEMM: Y[b][m][n] = sum_k A[m][k] * X[b][k][n] + bias[m]
//    64x64 tile, BK=32, fp32 LDS+FMA. N fixed = 2048. X fp32 or bf16.
__global__ __launch_bounds__(256) void gemm_f32(
    const float* __restrict__ A, const void* __restrict__ X, int xIsBf16,
    const float* __restrict__ bias, float* __restrict__ Y, int M, int K)
{
  __shared__ float Asm[64][33];
  __shared__ float Bsm[32][65];
  int b = blockIdx.z;
  int m0 = blockIdx.y * 64;
  int n0 = blockIdx.x * 64;
  int tid = threadIdx.x;
  int tx = tid & 15, ty = tid >> 4;
  float acc[4][4] = {};
  const float* Ab = A + (size_t)m0 * K;
  size_t xbase = (size_t)b * K * 2048;
  const float* Xf = (const float*)X + xbase;
  const u16*   Xh = (const u16*)X + xbase;
  for (int kt = 0; kt < K; kt += 32) {
#pragma unroll
    for (int p = 0; p < 8; ++p) {                     // A tile 64x32
      int i = tid + 256 * p;
      int mi = i >> 5, ki = i & 31;
      Asm[mi][ki] = Ab[(size_t)mi * K + kt + ki];
    }
#pragma unroll
    for (int p = 0; p < 8; ++p) {                     // B tile 32x64
      int i = tid + 256 * p;
      int ki = i >> 6, ni = i & 63;
      size_t gi = (size_t)(kt + ki) * 2048 + n0 + ni;
      Bsm[ki][ni] = xIsBf16 ? bf2f(Xh[gi]) : Xf[gi];
    }
    __syncthreads();
#pragma unroll 4
    for (int k = 0; k < 32; ++k) {
      float av[4], bv[4];
#pragma unroll
      for (int e = 0; e < 4; ++e) av[e] = Asm[ty * 4 + e][k];
#pragma unroll
      for (int e = 0; e < 4; ++e) bv[e] = Bsm[k][tx * 4 + e];
#pragma unroll
      for (int i = 0; i < 4; ++i)
#pragma unroll
        for (int j = 0; j < 4; ++j)
          acc[i][j] += av[i] * bv[j];
    }
    __syncthreads();
  }
#pragma unroll
  for (int i = 0; i < 4; ++i) {
    int m = m0 + ty * 4 + i;
    float bv = bias[m];
#pragma unroll
    for (int j = 0; j < 4; ++j)
      Y[((size_t)b * M + m) * 2048 + n0 + tx * 4 + j] = acc[i][j] + bv;
  }
}

// ---------------------------------------------------------------------------
// 6. GroupNorm stats per (b, group) on fp32 Y: contiguous cpg*2048 floats
__global__ void stats_kernel(const float* __restrict__ Y, float* __restrict__ stats,
                             int C, int cpg) {
  int g = blockIdx.x, b = blockIdx.y, tid = threadIdx.x;
  const float* base = Y + ((size_t)b * C + (size_t)g * cpg) * 2048;
  int n = cpg * 2048;
  float s = 0.f, ss = 0.f;
  for (int i = tid; i < n; i += 256) { float v = base[i]; s += v; ss += v * v; }
  __shared__ float s1[256], s2[256];
  s1[tid] = s; s2[tid] = ss;
  __syncthreads();
  for (int st = 128; st > 0; st >>= 1) {
    if (tid < st) { s1[tid] += s1[tid + st]; s2[tid] += s2[tid + st]; }
    __syncthreads();
  }
  if (tid == 0) {
    float fn = (float)n;
    float mu = s1[0] / fn;
    float var = s2[0] / fn - mu * mu;
    float rs = 1.0f / sqrtf(var + 1e-5f);
    stats[(b * 32 + g) * 2] = mu;
    stats[(b * 32 + g) * 2 + 1] = rs;
  }
}

// ---------------------------------------------------------------------------
// 7. GN + ReLU from fp32 Y. Optionally writes:
//    - bf16 staging to X3[(b*2048 + chBase + ch)*2048 + t]  (x3dst != null)
//    - fp32 row-major output at outDst[i]                   (outDst != null)
__global__ void norm_kernel(const float* __restrict__ Y, const float* __restrict__ stats,
                            const float* __restrict__ gamma, const float* __restrict__ beta,
                            int cMask, int bShift, int gShift,
                            u16* __restrict__ x3dst, int chBase,
                            float* __restrict__ outDst) {
  int i = blockIdx.x * 256 + threadIdx.x;
  int t = i & 2047;
  int ch = (i >> 11) & cMask;
  int b = i >> bShift;
  int gI = (b * 32 + (ch >> gShift)) * 2;
  float mu = stats[gI], rs = stats[gI + 1];
  float xn = (Y[i] - mu) * rs * gamma[ch] + beta[ch];
  float o = relu(xn);
  if (x3dst) x3dst[((size_t)b * 2048 + chBase + ch) * 2048 + t] = f2bf(o);
  if (outDst) outDst[i] = o;
}

// ---------------------------------------------------------------------------
extern "C" void kernel_launch(void* const* d_in, const int* in_sizes, int n_in,
                              void* d_out, int out_size, void* d_ws, size_t ws_size,
                              hipStream_t stream) {
  const float* feature = (const float*)d_in[0];
  const float* frame   = (const float*)d_in[1];
  const float* W1 = (const float*)d_in[2];
  const float* b1 = (const float*)d_in[3];
  const float* g1 = (const float*)d_in[4];
  const float* be1 = (const float*)d_in[5];
  const float* W2 = (const float*)d_in[6];
  const float* b2 = (const float*)d_in[7];
  const float* g2 = (const float*)d_in[8];
  const float* be2 = (const float*)d_in[9];
  const float* W3 = (const float*)d_in[10];
  const float* b3 = (const float*)d_in[11];
  const float* g3 = (const float*)d_in[12];
  const float* be3 = (const float*)d_in[13];

  char* ws = (char*)d_ws;
  u16*    X3    = (u16*)(ws + 0);                 // 32 MiB (B,2048c,2048t) bf16
  float*  Y1f   = (float*)(ws + 33554432);        // 16 MiB (B,512,2048) f32 (also Y3)
  float*  Y2f   = (float*)(ws + 50331648);        // 32 MiB (B,1024,2048) f32
  float*  Y3f   = Y1f;                            // Y1 dead before gemm3
  double* meanD = (double*)(ws + 83886080);       // 32 KiB
  int*    cdf   = (int*)(ws + 83918848);
  int*    idx   = (int*)(ws + 83935232);
  float*  st1   = (float*)(ws + 83943424);
  float*  st2   = (float*)(ws + 83944448);
  float*  st3   = (float*)(ws + 83945472);

  // OUTPUTS ARE FP32 (reference dtype is float32): mixed (B,512,2048) then
  // feat (B,1024,2048), concatenated flat.
  float* outMixed = (float*)d_out;
  float* outFeat  = outMixed + (size_t)4 * 512 * 2048;

  colmeanD_kernel<<<16, 256, 0, stream>>>(frame, meanD);
  scanD_kernel<<<1, 256, 0, stream>>>(meanD, cdf);
  argmin_kernel<<<2048, 256, 0, stream>>>(cdf, idx);
  gather_kernel<<<dim3(512, 4), 256, 0, stream>>>(frame, idx, X3);

  gemm_f32<<<dim3(32, 8, 4), 256, 0, stream>>>(W1, feature, 0, b1, Y1f, 512, 512);
  gemm_f32<<<dim3(32, 16, 4), 256, 0, stream>>>(W2, feature, 0, b2, Y2f, 1024, 512);
  stats_kernel<<<dim3(32, 4), 256, 0, stream>>>(Y1f, st1, 512, 16);
  stats_kernel<<<dim3(32, 4), 256, 0, stream>>>(Y2f, st2, 1024, 32);
  // fm_short -> X3 rows 1536..2047 ; feat -> X3 rows 512..1535 + outFeat(f32)
  norm_kernel<<<16384, 256, 0, stream>>>(Y1f, st1, g1, be1, 511, 20, 4,
                                         X3, 1536, (float*)nullptr);
  norm_kernel<<<32768, 256, 0, stream>>>(Y2f, st2, g2, be2, 1023, 21, 5,
                                         X3, 512, outFeat);
  gemm_f32<<<dim3(32, 8, 4), 256, 0, stream>>>(W3, X3, 1, b3, Y3f, 512, 2048);
  stats_kernel<<<dim3(32, 4), 256, 0, stream>>>(Y3f, st3, 512, 16);
  norm_kernel<<<16384, 256, 0, stream>>>(Y3f, st3, g3, be3, 511, 20, 4,
                                         (u16*)nullptr, 0, outMixed);
}

// Round 6
// 415.184 us; speedup vs baseline: 2.7767x; 2.7767x over previous
//
#include <hip/hip_runtime.h>

typedef unsigned short u16;
typedef unsigned int   u32;
typedef __attribute__((ext_vector_type(8))) short short8;
typedef __attribute__((ext_vector_type(4))) float f32x4;

__device__ __forceinline__ float bf2f(u16 v) {
  return __uint_as_float(((u32)v) << 16);
}
__device__ __forceinline__ u16 f2bf(float f) {
  u32 u = __float_as_uint(f);
  u32 r = (u + 0x7FFFu + ((u >> 16) & 1u)) >> 16;   // RNE
  return (u16)r;
}
// NaN-propagating ReLU (fmaxf(NaN,0)=0 would hide poison as zeros)
__device__ __forceinline__ float relu(float x) { return x < 0.f ? 0.f : x; }

// async global->LDS, 16B/lane; LDS dest = wave-uniform base + lane*16
__device__ __forceinline__ void gld16(const void* g, void* l) {
  __builtin_amdgcn_global_load_lds((const __attribute__((address_space(1))) u32*)g,
                                   (__attribute__((address_space(3))) u32*)l, 16, 0, 0);
}

// ---------------------------------------------------------------------------
// 1. column means of frame batch 0 over c, float64 accumulate, /512 exact.
__global__ void colmeanD_kernel(const float* __restrict__ frame, double* __restrict__ meanD) {
  int tf = blockIdx.x * 256 + threadIdx.x;           // 4096 total
  const float* f0 = frame + tf;
  double s = 0.0;
  for (int c = 0; c < 512; ++c) s += (double)f0[(size_t)c * 4096];
  meanD[tf] = s / 512.0;
}

// ---------------------------------------------------------------------------
// 2. float64: S = sum; q = meanD/S; cumsum; cdf = min(int(c*2048), 2047).
__global__ void scanD_kernel(const double* __restrict__ meanD, int* __restrict__ cdf) {
  __shared__ double part[256];
  __shared__ double base[256];
  __shared__ double Ss;
  int tid = threadIdx.x;
  double loc[16];
  double s = 0.0;
#pragma unroll
  for (int i = 0; i < 16; ++i) { loc[i] = meanD[tid * 16 + i]; s += loc[i]; }
  part[tid] = s;
  __syncthreads();
  if (tid == 0) {
    double t = 0.0;
    for (int i = 0; i < 256; ++i) t += part[i];
    Ss = t;
  }
  __syncthreads();
  double S = Ss;
  s = 0.0;
#pragma unroll
  for (int i = 0; i < 16; ++i) { loc[i] = loc[i] / S; s += loc[i]; }
  part[tid] = s;
  __syncthreads();
  if (tid == 0) {
    double c = 0.0;
    for (int i = 0; i < 256; ++i) { base[i] = c; c += part[i]; }
  }
  __syncthreads();
  double c = base[tid];
#pragma unroll
  for (int i = 0; i < 16; ++i) {
    c += loc[i];
    int iv = (int)(c * 2048.0);                      // trunc = astype(int32)
    cdf[tid * 16 + i] = iv < 2047 ? iv : 2047;
  }
}

// ---------------------------------------------------------------------------
// 3. idx[target] = first argmin_j |cdf[j]-target|
__global__ void argmin_kernel(const int* __restrict__ cdf, int* __restrict__ idx) {
  __shared__ int sd[256], sj[256];
  int target = blockIdx.x;                            // 2048 blocks
  int tid = threadIdx.x;
  int best = 0x7fffffff, bj = 0x7fffffff;
  for (int j = tid; j < 4096; j += 256) {
    int d = cdf[j] - target; d = d < 0 ? -d : d;
    if (d < best) { best = d; bj = j; }               // strict < keeps first
  }
  sd[tid] = best; sj[tid] = bj;
  __syncthreads();
  for (int s = 128; s > 0; s >>= 1) {
    if (tid < s) {
      if (sd[tid+s] < sd[tid] || (sd[tid+s] == sd[tid] && sj[tid+s] < sj[tid])) {
        sd[tid] = sd[tid+s]; sj[tid] = sj[tid+s];
      }
    }
    __syncthreads();
  }
  if (tid == 0) idx[target] = sj[0];
}

// ---------------------------------------------------------------------------
// 4. gather transposed: X3T[b][t][c] = bf16(frame[b][c][idx[t]]), c in [0,512)
//    X3T is (B, 2048t, 2048c); sampled occupies cols 0..511.
__global__ void gatherT_kernel(const float* __restrict__ frame, const int* __restrict__ idx,
                               u16* __restrict__ X3T) {
  __shared__ u16 tile[64][65];
  __shared__ int sidx[64];
  int cb = blockIdx.x * 64, t0 = blockIdx.y * 64, b = blockIdx.z;
  int tid = threadIdx.x;
  if (tid < 64) {
    int it = idx[t0 + tid];
    sidx[tid] = it < 0 ? 0 : (it > 4095 ? 4095 : it);
  }
  __syncthreads();
  const float* fb = frame + (size_t)b * 512 * 4096;
  for (int i = tid; i < 4096; i += 256) {
    int r = i >> 6, tt = i & 63;        // r = c-local, tt = t-local
    tile[tt][r] = f2bf(fb[(size_t)(cb + r) * 4096 + sidx[tt]]);
  }
  __syncthreads();
  u16* xb = X3T + (size_t)b * 2048 * 2048;
  for (int i = tid; i < 4096; i += 256) {
    int r = i >> 6, cc = i & 63;        // r = t-local, cc = c-local
    xb[(size_t)(t0 + r) * 2048 + cb + cc] = tile[r][cc];
  }
}

// ---------------------------------------------------------------------------
// 5. feature (B,512c,2048t) fp32 -> featT (B,2048t,512c) bf16, LDS 64x64
__global__ void transposeCT_kernel(const float* __restrict__ X, u16* __restrict__ XT) {
  __shared__ u16 tile[64][65];
  int cb = blockIdx.x * 64, t0 = blockIdx.y * 64, b = blockIdx.z;
  int tid = threadIdx.x;
  const float* xb = X + (size_t)b * 512 * 2048;
  for (int i = tid; i < 4096; i += 256) {
    int r = i >> 6, tt = i & 63;        // coalesced along t
    tile[tt][r] = f2bf(xb[(size_t)(cb + r) * 2048 + t0 + tt]);
  }
  __syncthreads();
  u16* xtb = XT + (size_t)b * 2048 * 512;
  for (int i = tid; i < 4096; i += 256) {
    int r = i >> 6, cc = i & 63;
    xtb[(size_t)(t0 + r) * 512 + cb + cc] = tile[r][cc];
  }
}

// ---------------------------------------------------------------------------
// 6. weight fp32 -> bf16
__global__ void convW_kernel(const float* __restrict__ src, u16* __restrict__ dst, int n) {
  int i = blockIdx.x * 256 + threadIdx.x;
  if (i < n) dst[i] = f2bf(src[i]);
}

// ---------------------------------------------------------------------------
// 7. m97-style GEMM: Y[b][m][n] = sum_k A[m][k]*Bt[b][n][k] + bias[m]
//    128x128 tile, BK=32, 4 waves, global_load_lds 16B, mfma 16x16x32 bf16.
__global__ __launch_bounds__(256) void gemm_bt(
    const u16* __restrict__ A, const u16* __restrict__ Bt,
    const float* __restrict__ bias, float* __restrict__ Y,
    int M, int N, int K)
{
  __shared__ short As[4096];   // [128 m][32 k]
  __shared__ short Bs[4096];   // [128 n][32 k]
  const int tid = threadIdx.x;
  const int lane = tid & 63;
  const int w = tid >> 6;
  const int nt = blockIdx.x, mt = blockIdx.y, bb = blockIdx.z;

  const u16* Ab = A + (size_t)mt * 128 * K;
  const u16* Bb = Bt + ((size_t)bb * N + (size_t)nt * 128) * K;

  const int lm = lane & 15, lq = lane >> 4;
  const int wrow = w >> 1, wcol = w & 1;

  f32x4 acc[4][4] = {};

  for (int kt = 0; kt < K; kt += 32) {
    __syncthreads();
#pragma unroll
    for (int p = 0; p < 2; ++p) {
      int q = w + 4 * p;
      int chunk = q * 64 + lane;          // 0..511, 16B each
      int row = chunk >> 2;
      int ko = (chunk & 3) << 3;
      gld16(Ab + (size_t)row * K + kt + ko, (char*)As + chunk * 16);
      gld16(Bb + (size_t)row * K + kt + ko, (char*)Bs + chunk * 16);
    }
    __syncthreads();                      // drains vmcnt before ds_read
    short8 af[4], bfv[4];
#pragma unroll
    for (int i = 0; i < 4; ++i)
      af[i] = *(const short8*)(As + ((wrow * 64 + i * 16 + lm) * 32 + lq * 8));
#pragma unroll
    for (int j = 0; j < 4; ++j)
      bfv[j] = *(const short8*)(Bs + ((wcol * 64 + j * 16 + lm) * 32 + lq * 8));
#pragma unroll
    for (int i = 0; i < 4; ++i)
#pragma unroll
      for (int j = 0; j < 4; ++j)
        acc[i][j] = __builtin_amdgcn_mfma_f32_16x16x32_bf16(af[i], bfv[j], acc[i][j], 0, 0, 0);
  }

  // C/D layout: col = lane&15, row = (lane>>4)*4 + reg   [m89/m91]
#pragma unroll
  for (int i = 0; i < 4; ++i) {
    int mbase = mt * 128 + wrow * 64 + i * 16 + lq * 4;
#pragma unroll
    for (int e = 0; e < 4; ++e) {
      int m = mbase + e;
      float bv = bias[m];
      float* yp = Y + ((size_t)bb * M + m) * N + nt * 128 + wcol * 64 + lm;
#pragma unroll
      for (int j = 0; j < 4; ++j)
        yp[j * 16] = acc[i][j][e] + bv;
    }
  }
}

// ---------------------------------------------------------------------------
// 8. GroupNorm stats per (b, group) on fp32 Y: contiguous cpg*2048 floats
__global__ void stats_kernel(const float* __restrict__ Y, float* __restrict__ stats,
                             int C, int cpg) {
  int g = blockIdx.x, b = blockIdx.y, tid = threadIdx.x;
  const float* base = Y + ((size_t)b * C + (size_t)g * cpg) * 2048;
  int n = cpg * 2048;
  float s = 0.f, ss = 0.f;
  for (int i = tid; i < n; i += 256) { float v = base[i]; s += v; ss += v * v; }
  __shared__ float s1[256], s2[256];
  s1[tid] = s; s2[tid] = ss;
  __syncthreads();
  for (int st = 128; st > 0; st >>= 1) {
    if (tid < st) { s1[tid] += s1[tid + st]; s2[tid] += s2[tid + st]; }
    __syncthreads();
  }
  if (tid == 0) {
    float fn = (float)n;
    float mu = s1[0] / fn;
    float var = s2[0] / fn - mu * mu;
    float rs = 1.0f / sqrtf(var + 1e-5f);
    stats[(b * 32 + g) * 2] = mu;
    stats[(b * 32 + g) * 2 + 1] = rs;
  }
}

// ---------------------------------------------------------------------------
// 9. GN+ReLU from fp32 Y; bf16 transposed into X3T[b][t][colBase+c] via LDS;
//    optional fp32 row-major copy to featOut (the `feat` output).
__global__ void normT_kernel(const float* __restrict__ Y, const float* __restrict__ stats,
                             const float* __restrict__ gamma, const float* __restrict__ beta,
                             int C, int gShift, u16* __restrict__ X3T, int colBase,
                             float* __restrict__ featOut) {
  __shared__ u16 tile[64][65];           // [t_local][c_local]
  int b = blockIdx.z, c0 = blockIdx.y * 64, t0 = blockIdx.x * 64;
  const float* yb = Y + (size_t)b * C * 2048;
  for (int i = threadIdx.x; i < 4096; i += 256) {
    int r = i >> 6, cc = i & 63;         // r: channel-local, cc: t-local
    int ch = c0 + r;
    int gI = (b * 32 + (ch >> gShift)) * 2;
    float mu = stats[gI], rs = stats[gI + 1];
    float v = yb[(size_t)ch * 2048 + t0 + cc];
    float o = relu((v - mu) * rs * gamma[ch] + beta[ch]);
    tile[cc][r] = f2bf(o);
    if (featOut) featOut[((size_t)b * C + ch) * 2048 + t0 + cc] = o;
  }
  __syncthreads();
  for (int i = threadIdx.x; i < 4096; i += 256) {
    int r = i >> 6, cc = i & 63;         // r: t-local, cc: c-local
    X3T[((size_t)b * 2048 + t0 + r) * 2048 + colBase + c0 + cc] = tile[r][cc];
  }
}

// ---------------------------------------------------------------------------
// 10. GN+ReLU elementwise for Y3 (B,512,2048) -> fp32 mixed output
__global__ void norm3_kernel(const float* __restrict__ Y, const float* __restrict__ stats,
                             const float* __restrict__ gamma, const float* __restrict__ beta,
                             float* __restrict__ out) {
  int i = blockIdx.x * 256 + threadIdx.x;            // 4,194,304 total
  int b = i >> 20;
  int ch = (i >> 11) & 511;
  int gI = (b * 32 + (ch >> 4)) * 2;
  float mu = stats[gI], rs = stats[gI + 1];
  out[i] = relu((Y[i] - mu) * rs * gamma[ch] + beta[ch]);
}

// ---------------------------------------------------------------------------
extern "C" void kernel_launch(void* const* d_in, const int* in_sizes, int n_in,
                              void* d_out, int out_size, void* d_ws, size_t ws_size,
                              hipStream_t stream) {
  const float* feature = (const float*)d_in[0];
  const float* frame   = (const float*)d_in[1];
  const float* W1 = (const float*)d_in[2];
  const float* b1 = (const float*)d_in[3];
  const float* g1 = (const float*)d_in[4];
  const float* be1 = (const float*)d_in[5];
  const float* W2 = (const float*)d_in[6];
  const float* b2 = (const float*)d_in[7];
  const float* g2 = (const float*)d_in[8];
  const float* be2 = (const float*)d_in[9];
  const float* W3 = (const float*)d_in[10];
  const float* b3 = (const float*)d_in[11];
  const float* g3 = (const float*)d_in[12];
  const float* be3 = (const float*)d_in[13];

  char* ws = (char*)d_ws;
  // Footprint kept within the R1/R5-proven ~88 MiB. Aliasing (stream-ordered):
  //   W1b -> head of Y2f (dead until gemm2, W1b dead after gemm1)
  //   W2b -> head of Y1f (Y1f dead after normT1; gemm3 overwrites it later)
  //   W3b -> head of Y2f (Y2f dead after normT2)
  u16*    X3T   = (u16*)(ws + 0);                 // 32 MiB (B,2048t,2048c) bf16
  float*  Y1f   = (float*)(ws + 33554432);        // 16 MiB (B,512,2048) f32 (also Y3)
  float*  Y2f   = (float*)(ws + 50331648);        // 32 MiB (B,1024,2048) f32
  float*  Y3f   = Y1f;
  u16*    featT = (u16*)(ws + 83886080);          //  8 MiB (B,2048,512) bf16
  u16*    W1b   = (u16*)(ws + 50331648);          // alias Y2f head (0.5 MiB)
  u16*    W2b   = (u16*)(ws + 33554432);          // alias Y1f head (1 MiB)
  u16*    W3b   = (u16*)(ws + 50331648);          // alias Y2f head (2 MiB)
  double* meanD = (double*)(ws + 92274688);       // 32 KiB
  int*    cdf   = (int*)(ws + 92307456);
  int*    idx   = (int*)(ws + 92323840);
  float*  st1   = (float*)(ws + 92340224);
  float*  st2   = (float*)(ws + 92341248);
  float*  st3   = (float*)(ws + 92342272);

  float* outMixed = (float*)d_out;                       // (B,512,2048) fp32
  float* outFeat  = outMixed + (size_t)4 * 512 * 2048;   // (B,1024,2048) fp32

  colmeanD_kernel<<<16, 256, 0, stream>>>(frame, meanD);
  scanD_kernel<<<1, 256, 0, stream>>>(meanD, cdf);
  argmin_kernel<<<2048, 256, 0, stream>>>(cdf, idx);
  gatherT_kernel<<<dim3(8, 32, 4), 256, 0, stream>>>(frame, idx, X3T);
  transposeCT_kernel<<<dim3(8, 32, 4), 256, 0, stream>>>(feature, featT);

  convW_kernel<<<1024, 256, 0, stream>>>(W1, W1b, 262144);
  gemm_bt<<<dim3(16, 4, 4), 256, 0, stream>>>(W1b, featT, b1, Y1f, 512, 2048, 512);
  stats_kernel<<<dim3(32, 4), 256, 0, stream>>>(Y1f, st1, 512, 16);
  normT_kernel<<<dim3(32, 8, 4), 256, 0, stream>>>(Y1f, st1, g1, be1, 512, 4,
                                                   X3T, 1536, (float*)nullptr);
  convW_kernel<<<2048, 256, 0, stream>>>(W2, W2b, 524288);
  gemm_bt<<<dim3(16, 8, 4), 256, 0, stream>>>(W2b, featT, b2, Y2f, 1024, 2048, 512);
  stats_kernel<<<dim3(32, 4), 256, 0, stream>>>(Y2f, st2, 1024, 32);
  normT_kernel<<<dim3(32, 16, 4), 256, 0, stream>>>(Y2f, st2, g2, be2, 1024, 5,
                                                    X3T, 512, outFeat);
  convW_kernel<<<4096, 256, 0, stream>>>(W3, W3b, 1048576);
  gemm_bt<<<dim3(16, 4, 4), 256, 0, stream>>>(W3b, X3T, b3, Y3f, 512, 2048, 2048);
  stats_kernel<<<dim3(32, 4), 256, 0, stream>>>(Y3f, st3, 512, 16);
  norm3_kernel<<<16384, 256, 0, stream>>>(Y3f, st3, g3, be3, outMixed);
}

// Round 7
// 308.802 us; speedup vs baseline: 3.7333x; 1.3445x over previous
//
#include <hip/hip_runtime.h>

typedef unsigned short u16;
typedef unsigned int   u32;
typedef __attribute__((ext_vector_type(8))) short short8;
typedef __attribute__((ext_vector_type(4))) float f32x4;

__device__ __forceinline__ float bf2f(u16 v) {
  return __uint_as_float(((u32)v) << 16);
}
__device__ __forceinline__ u16 f2bf(float f) {
  u32 u = __float_as_uint(f);
  u32 r = (u + 0x7FFFu + ((u >> 16) & 1u)) >> 16;   // RNE
  return (u16)r;
}
// NaN-propagating ReLU (fmaxf(NaN,0)=0 would hide poison as zeros)
__device__ __forceinline__ float relu(float x) { return x < 0.f ? 0.f : x; }

// async global->LDS, 16B/lane; LDS dest = wave-uniform base + lane*16
__device__ __forceinline__ void gld16(const void* g, void* l) {
  __builtin_amdgcn_global_load_lds((const __attribute__((address_space(1))) u32*)g,
                                   (__attribute__((address_space(3))) u32*)l, 16, 0, 0);
}

// ---------------------------------------------------------------------------
// 1a. partial column sums of frame batch 0: chunk ch sums c in [ch*64,ch*64+64)
//     sequentially in f64. partD[ch*4096 + tf].
__global__ void colmean_part_kernel(const float* __restrict__ frame,
                                    double* __restrict__ partD) {
  int tf = blockIdx.x * 256 + threadIdx.x;           // 4096
  int ch = blockIdx.y;                               // 8 chunks
  const float* f0 = frame + tf + (size_t)ch * 64 * 4096;
  double s = 0.0;
  for (int c = 0; c < 64; ++c) s += (double)f0[(size_t)c * 4096];
  partD[ch * 4096 + tf] = s;
}

// ---------------------------------------------------------------------------
// 2. f64: mean = (in-order chunk combine)/512; S = sum; q = mean/S; cumsum;
//    cdf = min(int(c*2048), 2047).
__global__ void scanD_kernel(const double* __restrict__ partD, int* __restrict__ cdf) {
  __shared__ double part[256];
  __shared__ double base[256];
  __shared__ double Ss;
  int tid = threadIdx.x;
  double loc[16];
  double s = 0.0;
#pragma unroll
  for (int i = 0; i < 16; ++i) {
    int tf = tid * 16 + i;
    double m = 0.0;
#pragma unroll
    for (int ch = 0; ch < 8; ++ch) m += partD[ch * 4096 + tf];  // in c-order
    loc[i] = m / 512.0;
    s += loc[i];
  }
  part[tid] = s;
  __syncthreads();
  if (tid == 0) {
    double t = 0.0;
    for (int i = 0; i < 256; ++i) t += part[i];
    Ss = t;
  }
  __syncthreads();
  double S = Ss;
  s = 0.0;
#pragma unroll
  for (int i = 0; i < 16; ++i) { loc[i] = loc[i] / S; s += loc[i]; }
  part[tid] = s;
  __syncthreads();
  if (tid == 0) {
    double c = 0.0;
    for (int i = 0; i < 256; ++i) { base[i] = c; c += part[i]; }
  }
  __syncthreads();
  double c = base[tid];
#pragma unroll
  for (int i = 0; i < 16; ++i) {
    c += loc[i];
    int iv = (int)(c * 2048.0);                      // trunc = astype(int32)
    cdf[tid * 16 + i] = iv < 2047 ? iv : 2047;
  }
}

// ---------------------------------------------------------------------------
// 3. idx[target] = first argmin_j |cdf[j]-target|
__global__ void argmin_kernel(const int* __restrict__ cdf, int* __restrict__ idx) {
  __shared__ int sd[256], sj[256];
  int target = blockIdx.x;                            // 2048 blocks
  int tid = threadIdx.x;
  int best = 0x7fffffff, bj = 0x7fffffff;
  for (int j = tid; j < 4096; j += 256) {
    int d = cdf[j] - target; d = d < 0 ? -d : d;
    if (d < best) { best = d; bj = j; }               // strict < keeps first
  }
  sd[tid] = best; sj[tid] = bj;
  __syncthreads();
  for (int s = 128; s > 0; s >>= 1) {
    if (tid < s) {
      if (sd[tid+s] < sd[tid] || (sd[tid+s] == sd[tid] && sj[tid+s] < sj[tid])) {
        sd[tid] = sd[tid+s]; sj[tid] = sj[tid+s];
      }
    }
    __syncthreads();
  }
  if (tid == 0) idx[target] = sj[0];
}

// ---------------------------------------------------------------------------
// 4. gather transposed: X3T[b][t][c] = bf16(frame[b][c][idx[t]]), c in [0,512)
__global__ void gatherT_kernel(const float* __restrict__ frame, const int* __restrict__ idx,
                               u16* __restrict__ X3T) {
  __shared__ u16 tile[64][65];
  __shared__ int sidx[64];
  int cb = blockIdx.x * 64, t0 = blockIdx.y * 64, b = blockIdx.z;
  int tid = threadIdx.x;
  if (tid < 64) {
    int it = idx[t0 + tid];
    sidx[tid] = it < 0 ? 0 : (it > 4095 ? 4095 : it);
  }
  __syncthreads();
  const float* fb = frame + (size_t)b * 512 * 4096;
  for (int i = tid; i < 4096; i += 256) {
    int r = i >> 6, tt = i & 63;        // r = c-local, tt = t-local
    tile[tt][r] = f2bf(fb[(size_t)(cb + r) * 4096 + sidx[tt]]);
  }
  __syncthreads();
  u16* xb = X3T + (size_t)b * 2048 * 2048;
  for (int i = tid; i < 4096; i += 256) {
    int r = i >> 6, cc = i & 63;        // r = t-local, cc = c-local
    xb[(size_t)(t0 + r) * 2048 + cb + cc] = tile[r][cc];
  }
}

// ---------------------------------------------------------------------------
// 5. feature (B,512c,2048t) fp32 -> featT (B,2048t,512c) bf16, LDS 64x64
__global__ void transposeCT_kernel(const float* __restrict__ X, u16* __restrict__ XT) {
  __shared__ u16 tile[64][65];
  int cb = blockIdx.x * 64, t0 = blockIdx.y * 64, b = blockIdx.z;
  int tid = threadIdx.x;
  const float* xb = X + (size_t)b * 512 * 2048;
  for (int i = tid; i < 4096; i += 256) {
    int r = i >> 6, tt = i & 63;        // coalesced along t
    tile[tt][r] = f2bf(xb[(size_t)(cb + r) * 2048 + t0 + tt]);
  }
  __syncthreads();
  u16* xtb = XT + (size_t)b * 2048 * 512;
  for (int i = tid; i < 4096; i += 256) {
    int r = i >> 6, cc = i & 63;
    xtb[(size_t)(t0 + r) * 512 + cb + cc] = tile[r][cc];
  }
}

// ---------------------------------------------------------------------------
// 6. weight fp32 -> bf16
__global__ void convW_kernel(const float* __restrict__ src, u16* __restrict__ dst, int n) {
  int i = blockIdx.x * 256 + threadIdx.x;
  if (i < n) dst[i] = f2bf(src[i]);
}

// ---------------------------------------------------------------------------
// 7. m97-style GEMM: Y[b][m][n] = sum_k A[m][k]*Bt[b][n][k] + bias[m]
//    128x128 tile, BK=32, 4 waves, global_load_lds 16B, mfma 16x16x32 bf16.
__global__ __launch_bounds__(256) void gemm_bt(
    const u16* __restrict__ A, const u16* __restrict__ Bt,
    const float* __restrict__ bias, float* __restrict__ Y,
    int M, int N, int K)
{
  __shared__ short As[4096];   // [128 m][32 k]
  __shared__ short Bs[4096];   // [128 n][32 k]
  const int tid = threadIdx.x;
  const int lane = tid & 63;
  const int w = tid >> 6;
  const int nt = blockIdx.x, mt = blockIdx.y, bb = blockIdx.z;

  const u16* Ab = A + (size_t)mt * 128 * K;
  const u16* Bb = Bt + ((size_t)bb * N + (size_t)nt * 128) * K;

  const int lm = lane & 15, lq = lane >> 4;
  const int wrow = w >> 1, wcol = w & 1;

  f32x4 acc[4][4] = {};

  for (int kt = 0; kt < K; kt += 32) {
    __syncthreads();
#pragma unroll
    for (int p = 0; p < 2; ++p) {
      int q = w + 4 * p;
      int chunk = q * 64 + lane;          // 0..511, 16B each
      int row = chunk >> 2;
      int ko = (chunk & 3) << 3;
      gld16(Ab + (size_t)row * K + kt + ko, (char*)As + chunk * 16);
      gld16(Bb + (size_t)row * K + kt + ko, (char*)Bs + chunk * 16);
    }
    __syncthreads();                      // drains vmcnt before ds_read
    short8 af[4], bfv[4];
#pragma unroll
    for (int i = 0; i < 4; ++i)
      af[i] = *(const short8*)(As + ((wrow * 64 + i * 16 + lm) * 32 + lq * 8));
#pragma unroll
    for (int j = 0; j < 4; ++j)
      bfv[j] = *(const short8*)(Bs + ((wcol * 64 + j * 16 + lm) * 32 + lq * 8));
#pragma unroll
    for (int i = 0; i < 4; ++i)
#pragma unroll
      for (int j = 0; j < 4; ++j)
        acc[i][j] = __builtin_amdgcn_mfma_f32_16x16x32_bf16(af[i], bfv[j], acc[i][j], 0, 0, 0);
  }

  // C/D layout: col = lane&15, row = (lane>>4)*4 + reg   [m89/m91]
#pragma unroll
  for (int i = 0; i < 4; ++i) {
    int mbase = mt * 128 + wrow * 64 + i * 16 + lq * 4;
#pragma unroll
    for (int e = 0; e < 4; ++e) {
      int m = mbase + e;
      float bv = bias[m];
      float* yp = Y + ((size_t)bb * M + m) * N + nt * 128 + wcol * 64 + lm;
#pragma unroll
      for (int j = 0; j < 4; ++j)
        yp[j * 16] = acc[i][j][e] + bv;
    }
  }
}

// ---------------------------------------------------------------------------
// 8a. two-stage GN stats, stage 1: one block per (chunk, group, b); each block
//     reduces 4096 contiguous floats and atomicAdds (sum, sumsq) partials.
__global__ void stats_part_kernel(const float* __restrict__ Y, float* __restrict__ raw,
                                  int C, int cpg) {
  int chunk = blockIdx.x, g = blockIdx.y, b = blockIdx.z, tid = threadIdx.x;
  const float* base = Y + ((size_t)b * C + (size_t)g * cpg) * 2048 + (size_t)chunk * 4096;
  float s = 0.f, ss = 0.f;
#pragma unroll
  for (int i = 0; i < 16; ++i) {
    float v = base[tid + 256 * i];
    s += v; ss += v * v;
  }
  __shared__ float s1[256], s2[256];
  s1[tid] = s; s2[tid] = ss;
  __syncthreads();
  for (int st = 128; st > 0; st >>= 1) {
    if (tid < st) { s1[tid] += s1[tid + st]; s2[tid] += s2[tid + st]; }
    __syncthreads();
  }
  if (tid == 0) {
    atomicAdd(&raw[(b * 32 + g) * 2],     s1[0]);
    atomicAdd(&raw[(b * 32 + g) * 2 + 1], s2[0]);
  }
}

// 8b. stage 2: finalize mu, rs per (b, group). 128 entries.
__global__ void stats_fin_kernel(const float* __restrict__ raw, float* __restrict__ stats,
                                 float n) {
  int i = threadIdx.x;                                // 128
  float mu = raw[i * 2] / n;
  float var = raw[i * 2 + 1] / n - mu * mu;
  stats[i * 2] = mu;
  stats[i * 2 + 1] = 1.0f / sqrtf(var + 1e-5f);
}

// ---------------------------------------------------------------------------
// 9. GN+ReLU from fp32 Y; bf16 transposed into X3T[b][t][colBase+c] via LDS;
//    optional fp32 row-major copy to featOut (the `feat` output).
__global__ void normT_kernel(const float* __restrict__ Y, const float* __restrict__ stats,
                             const float* __restrict__ gamma, const float* __restrict__ beta,
                             int C, int gShift, u16* __restrict__ X3T, int colBase,
                             float* __restrict__ featOut) {
  __shared__ u16 tile[64][65];           // [t_local][c_local]
  int b = blockIdx.z, c0 = blockIdx.y * 64, t0 = blockIdx.x * 64;
  const float* yb = Y + (size_t)b * C * 2048;
  for (int i = threadIdx.x; i < 4096; i += 256) {
    int r = i >> 6, cc = i & 63;         // r: channel-local, cc: t-local
    int ch = c0 + r;
    int gI = (b * 32 + (ch >> gShift)) * 2;
    float mu = stats[gI], rs = stats[gI + 1];
    float v = yb[(size_t)ch * 2048 + t0 + cc];
    float o = relu((v - mu) * rs * gamma[ch] + beta[ch]);
    tile[cc][r] = f2bf(o);
    if (featOut) featOut[((size_t)b * C + ch) * 2048 + t0 + cc] = o;
  }
  __syncthreads();
  for (int i = threadIdx.x; i < 4096; i += 256) {
    int r = i >> 6, cc = i & 63;         // r: t-local, cc: c-local
    X3T[((size_t)b * 2048 + t0 + r) * 2048 + colBase + c0 + cc] = tile[r][cc];
  }
}

// ---------------------------------------------------------------------------
// 10. GN+ReLU elementwise for Y3 (B,512,2048) -> fp32 mixed output
__global__ void norm3_kernel(const float* __restrict__ Y, const float* __restrict__ stats,
                             const float* __restrict__ gamma, const float* __restrict__ beta,
                             float* __restrict__ out) {
  int i = blockIdx.x * 256 + threadIdx.x;            // 4,194,304 total
  int b = i >> 20;
  int ch = (i >> 11) & 511;
  int gI = (b * 32 + (ch >> 4)) * 2;
  float mu = stats[gI], rs = stats[gI + 1];
  out[i] = relu((Y[i] - mu) * rs * gamma[ch] + beta[ch]);
}

// ---------------------------------------------------------------------------
extern "C" void kernel_launch(void* const* d_in, const int* in_sizes, int n_in,
                              void* d_out, int out_size, void* d_ws, size_t ws_size,
                              hipStream_t stream) {
  const float* feature = (const float*)d_in[0];
  const float* frame   = (const float*)d_in[1];
  const float* W1 = (const float*)d_in[2];
  const float* b1 = (const float*)d_in[3];
  const float* g1 = (const float*)d_in[4];
  const float* be1 = (const float*)d_in[5];
  const float* W2 = (const float*)d_in[6];
  const float* b2 = (const float*)d_in[7];
  const float* g2 = (const float*)d_in[8];
  const float* be2 = (const float*)d_in[9];
  const float* W3 = (const float*)d_in[10];
  const float* b3 = (const float*)d_in[11];
  const float* g3 = (const float*)d_in[12];
  const float* be3 = (const float*)d_in[13];

  char* ws = (char*)d_ws;
  // Aliasing (stream-ordered lifetimes):
  //   partD -> Y2f head (dead until gemm2; partD dead after scanD)
  //   W1b   -> Y2f head+1MiB (dead after gemm1, before gemm2)
  //   W2b   -> Y1f head (Y1f written by gemm1 AFTER convW2... see order below)
  //   W3b   -> Y2f head (Y2f dead after normT2)
  u16*    X3T   = (u16*)(ws + 0);                 // 32 MiB (B,2048t,2048c) bf16
  float*  Y1f   = (float*)(ws + 33554432);        // 16 MiB (B,512,2048) f32 (also Y3)
  float*  Y2f   = (float*)(ws + 50331648);        // 32 MiB (B,1024,2048) f32
  float*  Y3f   = Y1f;
  u16*    featT = (u16*)(ws + 83886080);          //  8 MiB (B,2048,512) bf16
  double* partD = (double*)(ws + 50331648);       // 256 KiB, alias Y2f head
  u16*    W1b   = (u16*)(ws + 50331648 + 1048576);// alias Y2f +1 MiB (0.5 MiB)
  u16*    W2b   = (u16*)(ws + 33554432);          // alias Y1f head (1 MiB)
  u16*    W3b   = (u16*)(ws + 50331648);          // alias Y2f head (2 MiB)
  int*    cdf   = (int*)(ws + 92307456);
  int*    idx   = (int*)(ws + 92323840);
  float*  raw1  = (float*)(ws + 92340224);        // 1 KiB each
  float*  raw2  = (float*)(ws + 92341248);
  float*  raw3  = (float*)(ws + 92342272);
  float*  st1   = (float*)(ws + 92343296);
  float*  st2   = (float*)(ws + 92344320);
  float*  st3   = (float*)(ws + 92345344);

  float* outMixed = (float*)d_out;                       // (B,512,2048) fp32
  float* outFeat  = outMixed + (size_t)4 * 512 * 2048;   // (B,1024,2048) fp32

  hipMemsetAsync(raw1, 0, 3 * 1024, stream);             // zero raw1/raw2/raw3

  colmean_part_kernel<<<dim3(16, 8), 256, 0, stream>>>(frame, partD);
  scanD_kernel<<<1, 256, 0, stream>>>(partD, cdf);
  argmin_kernel<<<2048, 256, 0, stream>>>(cdf, idx);
  gatherT_kernel<<<dim3(8, 32, 4), 256, 0, stream>>>(frame, idx, X3T);
  transposeCT_kernel<<<dim3(8, 32, 4), 256, 0, stream>>>(feature, featT);

  // convW2 BEFORE gemm1 (W2b aliases Y1f head, must be read out... no —
  // W2b is INPUT to gemm2 which runs after gemm1 writes Y1f. Conflict!
  // Resolution: convW2 writes W2b AFTER normT1 consumed Y1f? No — gemm2 needs
  // W2b while Y2f... Simplest safe order: keep W2b in its own space instead.
  // (see W2b placement: moved to dedicated region below featT)
  convW_kernel<<<1024, 256, 0, stream>>>(W1, W1b, 262144);
  gemm_bt<<<dim3(16, 4, 4), 256, 0, stream>>>(W1b, featT, b1, Y1f, 512, 2048, 512);
  stats_part_kernel<<<dim3(8, 32, 4), 256, 0, stream>>>(Y1f, raw1, 512, 16);
  stats_fin_kernel<<<1, 128, 0, stream>>>(raw1, st1, 32768.f);
  normT_kernel<<<dim3(32, 8, 4), 256, 0, stream>>>(Y1f, st1, g1, be1, 512, 4,
                                                   X3T, 1536, (float*)nullptr);
  convW_kernel<<<2048, 256, 0, stream>>>(W2, W2b, 524288);
  gemm_bt<<<dim3(16, 8, 4), 256, 0, stream>>>(W2b, featT, b2, Y2f, 1024, 2048, 512);
  stats_part_kernel<<<dim3(16, 32, 4), 256, 0, stream>>>(Y2f, raw2, 1024, 32);
  stats_fin_kernel<<<1, 128, 0, stream>>>(raw2, st2, 65536.f);
  normT_kernel<<<dim3(32, 16, 4), 256, 0, stream>>>(Y2f, st2, g2, be2, 1024, 5,
                                                    X3T, 512, outFeat);
  convW_kernel<<<4096, 256, 0, stream>>>(W3, W3b, 1048576);
  gemm_bt<<<dim3(16, 4, 4), 256, 0, stream>>>(W3b, X3T, b3, Y3f, 512, 2048, 2048);
  stats_part_kernel<<<dim3(8, 32, 4), 256, 0, stream>>>(Y3f, raw3, 512, 16);
  stats_fin_kernel<<<1, 128, 0, stream>>>(raw3, st3, 32768.f);
  norm3_kernel<<<16384, 256, 0, stream>>>(Y3f, st3, g3, be3, outMixed);
}

// Round 8
// 299.614 us; speedup vs baseline: 3.8478x; 1.0307x over previous
//
#include <hip/hip_runtime.h>

typedef unsigned short u16;
typedef unsigned int   u32;
typedef __attribute__((ext_vector_type(8))) short short8;
typedef __attribute__((ext_vector_type(4))) float f32x4;

__device__ __forceinline__ float bf2f(u16 v) {
  return __uint_as_float(((u32)v) << 16);
}
__device__ __forceinline__ u16 f2bf(float f) {
  u32 u = __float_as_uint(f);
  u32 r = (u + 0x7FFFu + ((u >> 16) & 1u)) >> 16;   // RNE
  return (u16)r;
}
// NaN-propagating ReLU (fmaxf(NaN,0)=0 would hide poison as zeros)
__device__ __forceinline__ float relu(float x) { return x < 0.f ? 0.f : x; }

// async global->LDS, 16B/lane; LDS dest = wave-uniform base + lane*16
__device__ __forceinline__ void gld16(const void* g, void* l) {
  __builtin_amdgcn_global_load_lds((const __attribute__((address_space(1))) u32*)g,
                                   (__attribute__((address_space(3))) u32*)l, 16, 0, 0);
}

// ---------------------------------------------------------------------------
// 1a. partial column sums of frame batch 0: chunk ch sums c in [ch*64,ch*64+64)
__global__ void colmean_part_kernel(const float* __restrict__ frame,
                                    double* __restrict__ partD) {
  int tf = blockIdx.x * 256 + threadIdx.x;           // 4096
  int ch = blockIdx.y;                               // 8 chunks
  const float* f0 = frame + tf + (size_t)ch * 64 * 4096;
  double s = 0.0;
  for (int c = 0; c < 64; ++c) s += (double)f0[(size_t)c * 4096];
  partD[ch * 4096 + tf] = s;
}

// ---------------------------------------------------------------------------
// 2. f64: mean = (in-order chunk combine)/512; S = sum; q = mean/S; cumsum;
//    cdf = min(int(c*2048), 2047).
__global__ void scanD_kernel(const double* __restrict__ partD, int* __restrict__ cdf) {
  __shared__ double part[256];
  __shared__ double base[256];
  __shared__ double Ss;
  int tid = threadIdx.x;
  double loc[16];
  double s = 0.0;
#pragma unroll
  for (int i = 0; i < 16; ++i) {
    int tf = tid * 16 + i;
    double m = 0.0;
#pragma unroll
    for (int ch = 0; ch < 8; ++ch) m += partD[ch * 4096 + tf];  // in c-order
    loc[i] = m / 512.0;
    s += loc[i];
  }
  part[tid] = s;
  __syncthreads();
  if (tid == 0) {
    double t = 0.0;
    for (int i = 0; i < 256; ++i) t += part[i];
    Ss = t;
  }
  __syncthreads();
  double S = Ss;
  s = 0.0;
#pragma unroll
  for (int i = 0; i < 16; ++i) { loc[i] = loc[i] / S; s += loc[i]; }
  part[tid] = s;
  __syncthreads();
  if (tid == 0) {
    double c = 0.0;
    for (int i = 0; i < 256; ++i) { base[i] = c; c += part[i]; }
  }
  __syncthreads();
  double c = base[tid];
#pragma unroll
  for (int i = 0; i < 16; ++i) {
    c += loc[i];
    int iv = (int)(c * 2048.0);                      // trunc = astype(int32)
    cdf[tid * 16 + i] = iv < 2047 ? iv : 2047;
  }
}

// ---------------------------------------------------------------------------
// 3. idx[target] = first argmin_j |cdf[j]-target|
__global__ void argmin_kernel(const int* __restrict__ cdf, int* __restrict__ idx) {
  __shared__ int sd[256], sj[256];
  int target = blockIdx.x;                            // 2048 blocks
  int tid = threadIdx.x;
  int best = 0x7fffffff, bj = 0x7fffffff;
  for (int j = tid; j < 4096; j += 256) {
    int d = cdf[j] - target; d = d < 0 ? -d : d;
    if (d < best) { best = d; bj = j; }               // strict < keeps first
  }
  sd[tid] = best; sj[tid] = bj;
  __syncthreads();
  for (int s = 128; s > 0; s >>= 1) {
    if (tid < s) {
      if (sd[tid+s] < sd[tid] || (sd[tid+s] == sd[tid] && sj[tid+s] < sj[tid])) {
        sd[tid] = sd[tid+s]; sj[tid] = sj[tid+s];
      }
    }
    __syncthreads();
  }
  if (tid == 0) idx[target] = sj[0];
}

// ---------------------------------------------------------------------------
// 4. gather transposed: X3T[b][t][c] = bf16(frame[b][c][idx[t]]), c in [0,512)
__global__ void gatherT_kernel(const float* __restrict__ frame, const int* __restrict__ idx,
                               u16* __restrict__ X3T) {
  __shared__ u16 tile[64][65];
  __shared__ int sidx[64];
  int cb = blockIdx.x * 64, t0 = blockIdx.y * 64, b = blockIdx.z;
  int tid = threadIdx.x;
  if (tid < 64) {
    int it = idx[t0 + tid];
    sidx[tid] = it < 0 ? 0 : (it > 4095 ? 4095 : it);
  }
  __syncthreads();
  const float* fb = frame + (size_t)b * 512 * 4096;
  for (int i = tid; i < 4096; i += 256) {
    int r = i >> 6, tt = i & 63;        // r = c-local, tt = t-local
    tile[tt][r] = f2bf(fb[(size_t)(cb + r) * 4096 + sidx[tt]]);
  }
  __syncthreads();
  u16* xb = X3T + (size_t)b * 2048 * 2048;
  for (int i = tid; i < 4096; i += 256) {
    int r = i >> 6, cc = i & 63;        // r = t-local, cc = c-local
    xb[(size_t)(t0 + r) * 2048 + cb + cc] = tile[r][cc];
  }
}

// ---------------------------------------------------------------------------
// 5. feature (B,512c,2048t) fp32 -> featT (B,2048t,512c) bf16, LDS 64x64
__global__ void transposeCT_kernel(const float* __restrict__ X, u16* __restrict__ XT) {
  __shared__ u16 tile[64][65];
  int cb = blockIdx.x * 64, t0 = blockIdx.y * 64, b = blockIdx.z;
  int tid = threadIdx.x;
  const float* xb = X + (size_t)b * 512 * 2048;
  for (int i = tid; i < 4096; i += 256) {
    int r = i >> 6, tt = i & 63;        // coalesced along t
    tile[tt][r] = f2bf(xb[(size_t)(cb + r) * 2048 + t0 + tt]);
  }
  __syncthreads();
  u16* xtb = XT + (size_t)b * 2048 * 512;
  for (int i = tid; i < 4096; i += 256) {
    int r = i >> 6, cc = i & 63;
    xtb[(size_t)(t0 + r) * 512 + cb + cc] = tile[r][cc];
  }
}

// ---------------------------------------------------------------------------
// 6. weight fp32 -> bf16
__global__ void convW_kernel(const float* __restrict__ src, u16* __restrict__ dst, int n) {
  int i = blockIdx.x * 256 + threadIdx.x;
  if (i < n) dst[i] = f2bf(src[i]);
}

// ---------------------------------------------------------------------------
// 7. GEMM: Y[b][m][n] = sum_k A[m][k]*Bt[b][n][k] + bias[m]
//    64x128 tile, 2 waves (each wave 64x64 = 4x4 frags, same as m97 per-wave),
//    BK=32, double-buffered LDS with prefetch-after-barrier, 1 barrier/K-step.
__global__ __launch_bounds__(128) void gemm_bt2(
    const u16* __restrict__ A, const u16* __restrict__ Bt,
    const float* __restrict__ bias, float* __restrict__ Y,
    int M, int N, int K)
{
  __shared__ short As[2][2048];   // [buf][64 m][32 k]
  __shared__ short Bs[2][4096];   // [buf][128 n][32 k]
  const int tid = threadIdx.x;
  const int lane = tid & 63;
  const int w = tid >> 6;          // 0..1 (n-half)
  const int nt = blockIdx.x, mt = blockIdx.y, bb = blockIdx.z;

  const u16* Ab = A + (size_t)mt * 64 * K;
  const u16* Bb = Bt + ((size_t)bb * N + (size_t)nt * 128) * K;

  const int lm = lane & 15, lq = lane >> 4;

  f32x4 acc[4][4] = {};
  const int nsteps = K >> 5;

  // stage one BK=32 tile: A 256 chunks (2/thread), B 512 chunks (4/thread);
  // per-wave lanes hit consecutive 16B LDS slots (gld16 contract).
  auto stage = [&](int buf, int kt) {
#pragma unroll
    for (int p = 0; p < 2; ++p) {
      int chunk = tid + 128 * p;
      int row = chunk >> 2, ko = (chunk & 3) << 3;
      gld16(Ab + (size_t)row * K + kt + ko, (char*)As[buf] + chunk * 16);
    }
#pragma unroll
    for (int p = 0; p < 4; ++p) {
      int chunk = tid + 128 * p;
      int row = chunk >> 2, ko = (chunk & 3) << 3;
      gld16(Bb + (size_t)row * K + kt + ko, (char*)Bs[buf] + chunk * 16);
    }
  };

  stage(0, 0);
  for (int s = 0; s < nsteps; ++s) {
    int cur = s & 1;
    __syncthreads();                 // drains vmcnt -> buf[cur] ready; WAR safe
    if (s + 1 < nsteps) stage(cur ^ 1, (s + 1) << 5);   // prefetch next tile
    short8 af[4], bfv[4];
#pragma unroll
    for (int i = 0; i < 4; ++i)
      af[i] = *(const short8*)(As[cur] + ((i * 16 + lm) * 32 + lq * 8));
#pragma unroll
    for (int j = 0; j < 4; ++j)
      bfv[j] = *(const short8*)(Bs[cur] + ((w * 64 + j * 16 + lm) * 32 + lq * 8));
#pragma unroll
    for (int i = 0; i < 4; ++i)
#pragma unroll
      for (int j = 0; j < 4; ++j)
        acc[i][j] = __builtin_amdgcn_mfma_f32_16x16x32_bf16(af[i], bfv[j], acc[i][j], 0, 0, 0);
  }

  // C/D layout: col = lane&15, row = (lane>>4)*4 + reg   [m89/m91]
#pragma unroll
  for (int i = 0; i < 4; ++i) {
    int mbase = mt * 64 + i * 16 + lq * 4;
#pragma unroll
    for (int e = 0; e < 4; ++e) {
      int m = mbase + e;
      float bv = bias[m];
      float* yp = Y + ((size_t)bb * M + m) * N + nt * 128 + w * 64 + lm;
#pragma unroll
      for (int j = 0; j < 4; ++j)
        yp[j * 16] = acc[i][j][e] + bv;
    }
  }
}

// ---------------------------------------------------------------------------
// 8a. two-stage GN stats, stage 1: one block per (chunk, group, b)
__global__ void stats_part_kernel(const float* __restrict__ Y, float* __restrict__ raw,
                                  int C, int cpg) {
  int chunk = blockIdx.x, g = blockIdx.y, b = blockIdx.z, tid = threadIdx.x;
  const float* base = Y + ((size_t)b * C + (size_t)g * cpg) * 2048 + (size_t)chunk * 4096;
  float s = 0.f, ss = 0.f;
#pragma unroll
  for (int i = 0; i < 16; ++i) {
    float v = base[tid + 256 * i];
    s += v; ss += v * v;
  }
  __shared__ float s1[256], s2[256];
  s1[tid] = s; s2[tid] = ss;
  __syncthreads();
  for (int st = 128; st > 0; st >>= 1) {
    if (tid < st) { s1[tid] += s1[tid + st]; s2[tid] += s2[tid + st]; }
    __syncthreads();
  }
  if (tid == 0) {
    atomicAdd(&raw[(b * 32 + g) * 2],     s1[0]);
    atomicAdd(&raw[(b * 32 + g) * 2 + 1], s2[0]);
  }
}

// 8b. stage 2: finalize mu, rs per (b, group). 128 entries.
__global__ void stats_fin_kernel(const float* __restrict__ raw, float* __restrict__ stats,
                                 float n) {
  int i = threadIdx.x;                                // 128
  float mu = raw[i * 2] / n;
  float var = raw[i * 2 + 1] / n - mu * mu;
  stats[i * 2] = mu;
  stats[i * 2 + 1] = 1.0f / sqrtf(var + 1e-5f);
}

// ---------------------------------------------------------------------------
// 9. GN+ReLU from fp32 Y; bf16 transposed into X3T[b][t][colBase+c] via LDS;
//    optional fp32 row-major copy to featOut (the `feat` output).
__global__ void normT_kernel(const float* __restrict__ Y, const float* __restrict__ stats,
                             const float* __restrict__ gamma, const float* __restrict__ beta,
                             int C, int gShift, u16* __restrict__ X3T, int colBase,
                             float* __restrict__ featOut) {
  __shared__ u16 tile[64][65];           // [t_local][c_local]
  int b = blockIdx.z, c0 = blockIdx.y * 64, t0 = blockIdx.x * 64;
  const float* yb = Y + (size_t)b * C * 2048;
  for (int i = threadIdx.x; i < 4096; i += 256) {
    int r = i >> 6, cc = i & 63;         // r: channel-local, cc: t-local
    int ch = c0 + r;
    int gI = (b * 32 + (ch >> gShift)) * 2;
    float mu = stats[gI], rs = stats[gI + 1];
    float v = yb[(size_t)ch * 2048 + t0 + cc];
    float o = relu((v - mu) * rs * gamma[ch] + beta[ch]);
    tile[cc][r] = f2bf(o);
    if (featOut) featOut[((size_t)b * C + ch) * 2048 + t0 + cc] = o;
  }
  __syncthreads();
  for (int i = threadIdx.x; i < 4096; i += 256) {
    int r = i >> 6, cc = i & 63;         // r: t-local, cc: c-local
    X3T[((size_t)b * 2048 + t0 + r) * 2048 + colBase + c0 + cc] = tile[r][cc];
  }
}

// ---------------------------------------------------------------------------
// 10. GN+ReLU elementwise for Y3 (B,512,2048) -> fp32 mixed output
__global__ void norm3_kernel(const float* __restrict__ Y, const float* __restrict__ stats,
                             const float* __restrict__ gamma, const float* __restrict__ beta,
                             float* __restrict__ out) {
  int i = blockIdx.x * 256 + threadIdx.x;            // 4,194,304 total
  int b = i >> 20;
  int ch = (i >> 11) & 511;
  int gI = (b * 32 + (ch >> 4)) * 2;
  float mu = stats[gI], rs = stats[gI + 1];
  out[i] = relu((Y[i] - mu) * rs * gamma[ch] + beta[ch]);
}

// ---------------------------------------------------------------------------
extern "C" void kernel_launch(void* const* d_in, const int* in_sizes, int n_in,
                              void* d_out, int out_size, void* d_ws, size_t ws_size,
                              hipStream_t stream) {
  const float* feature = (const float*)d_in[0];
  const float* frame   = (const float*)d_in[1];
  const float* W1 = (const float*)d_in[2];
  const float* b1 = (const float*)d_in[3];
  const float* g1 = (const float*)d_in[4];
  const float* be1 = (const float*)d_in[5];
  const float* W2 = (const float*)d_in[6];
  const float* b2 = (const float*)d_in[7];
  const float* g2 = (const float*)d_in[8];
  const float* be2 = (const float*)d_in[9];
  const float* W3 = (const float*)d_in[10];
  const float* b3 = (const float*)d_in[11];
  const float* g3 = (const float*)d_in[12];
  const float* be3 = (const float*)d_in[13];

  char* ws = (char*)d_ws;
  // Aliasing (stream-ordered lifetimes, proven layout from R7):
  //   partD -> Y2f head (dead until gemm2; partD dead after scanD)
  //   W1b   -> Y2f head+1MiB (dead after gemm1, before gemm2)
  //   W2b   -> Y1f head (convW2 runs after normT1 freed Y1f)
  //   W3b   -> Y2f head (Y2f dead after normT2)
  u16*    X3T   = (u16*)(ws + 0);                 // 32 MiB (B,2048t,2048c) bf16
  float*  Y1f   = (float*)(ws + 33554432);        // 16 MiB (B,512,2048) f32 (also Y3)
  float*  Y2f   = (float*)(ws + 50331648);        // 32 MiB (B,1024,2048) f32
  float*  Y3f   = Y1f;
  u16*    featT = (u16*)(ws + 83886080);          //  8 MiB (B,2048,512) bf16
  double* partD = (double*)(ws + 50331648);       // 256 KiB, alias Y2f head
  u16*    W1b   = (u16*)(ws + 50331648 + 1048576);// alias Y2f +1 MiB (0.5 MiB)
  u16*    W2b   = (u16*)(ws + 33554432);          // alias Y1f head (1 MiB)
  u16*    W3b   = (u16*)(ws + 50331648);          // alias Y2f head (2 MiB)
  int*    cdf   = (int*)(ws + 92307456);
  int*    idx   = (int*)(ws + 92323840);
  float*  raw1  = (float*)(ws + 92340224);        // 1 KiB each
  float*  raw2  = (float*)(ws + 92341248);
  float*  raw3  = (float*)(ws + 92342272);
  float*  st1   = (float*)(ws + 92343296);
  float*  st2   = (float*)(ws + 92344320);
  float*  st3   = (float*)(ws + 92345344);

  float* outMixed = (float*)d_out;                       // (B,512,2048) fp32
  float* outFeat  = outMixed + (size_t)4 * 512 * 2048;   // (B,1024,2048) fp32

  hipMemsetAsync(raw1, 0, 3 * 1024, stream);             // zero raw1/raw2/raw3

  colmean_part_kernel<<<dim3(16, 8), 256, 0, stream>>>(frame, partD);
  scanD_kernel<<<1, 256, 0, stream>>>(partD, cdf);
  argmin_kernel<<<2048, 256, 0, stream>>>(cdf, idx);
  gatherT_kernel<<<dim3(8, 32, 4), 256, 0, stream>>>(frame, idx, X3T);
  transposeCT_kernel<<<dim3(8, 32, 4), 256, 0, stream>>>(feature, featT);

  convW_kernel<<<1024, 256, 0, stream>>>(W1, W1b, 262144);
  gemm_bt2<<<dim3(16, 8, 4), 128, 0, stream>>>(W1b, featT, b1, Y1f, 512, 2048, 512);
  stats_part_kernel<<<dim3(8, 32, 4), 256, 0, stream>>>(Y1f, raw1, 512, 16);
  stats_fin_kernel<<<1, 128, 0, stream>>>(raw1, st1, 32768.f);
  normT_kernel<<<dim3(32, 8, 4), 256, 0, stream>>>(Y1f, st1, g1, be1, 512, 4,
                                                   X3T, 1536, (float*)nullptr);
  convW_kernel<<<2048, 256, 0, stream>>>(W2, W2b, 524288);
  gemm_bt2<<<dim3(16, 16, 4), 128, 0, stream>>>(W2b, featT, b2, Y2f, 1024, 2048, 512);
  stats_part_kernel<<<dim3(16, 32, 4), 256, 0, stream>>>(Y2f, raw2, 1024, 32);
  stats_fin_kernel<<<1, 128, 0, stream>>>(raw2, st2, 65536.f);
  normT_kernel<<<dim3(32, 16, 4), 256, 0, stream>>>(Y2f, st2, g2, be2, 1024, 5,
                                                    X3T, 512, outFeat);
  convW_kernel<<<4096, 256, 0, stream>>>(W3, W3b, 1048576);
  gemm_bt2<<<dim3(16, 8, 4), 128, 0, stream>>>(W3b, X3T, b3, Y3f, 512, 2048, 2048);
  stats_part_kernel<<<dim3(8, 32, 4), 256, 0, stream>>>(Y3f, raw3, 512, 16);
  stats_fin_kernel<<<1, 128, 0, stream>>>(raw3, st3, 32768.f);
  norm3_kernel<<<16384, 256, 0, stream>>>(Y3f, st3, g3, be3, outMixed);
}

// Round 9
// 285.533 us; speedup vs baseline: 4.0375x; 1.0493x over previous
//
#include <hip/hip_runtime.h>

typedef unsigned short u16;
typedef unsigned int   u32;
typedef __attribute__((ext_vector_type(8))) short short8;
typedef __attribute__((ext_vector_type(4))) float f32x4;

__device__ __forceinline__ float bf2f(u16 v) {
  return __uint_as_float(((u32)v) << 16);
}
__device__ __forceinline__ u16 f2bf(float f) {
  u32 u = __float_as_uint(f);
  u32 r = (u + 0x7FFFu + ((u >> 16) & 1u)) >> 16;   // RNE
  return (u16)r;
}
// NaN-propagating ReLU (fmaxf(NaN,0)=0 would hide poison as zeros)
__device__ __forceinline__ float relu(float x) { return x < 0.f ? 0.f : x; }

// async global->LDS, 16B/lane; LDS dest = wave-uniform base + lane*16
__device__ __forceinline__ void gld16(const void* g, void* l) {
  __builtin_amdgcn_global_load_lds((const __attribute__((address_space(1))) u32*)g,
                                   (__attribute__((address_space(3))) u32*)l, 16, 0, 0);
}

// ---------------------------------------------------------------------------
// 1a. partial column sums of frame batch 0: chunk ch sums c in [ch*64,ch*64+64)
__global__ void colmean_part_kernel(const float* __restrict__ frame,
                                    double* __restrict__ partD) {
  int tf = blockIdx.x * 256 + threadIdx.x;           // 4096
  int ch = blockIdx.y;                               // 8 chunks
  const float* f0 = frame + tf + (size_t)ch * 64 * 4096;
  double s = 0.0;
  for (int c = 0; c < 64; ++c) s += (double)f0[(size_t)c * 4096];
  partD[ch * 4096 + tf] = s;
}

// ---------------------------------------------------------------------------
// 2. f64: mean = (in-order chunk combine)/512; S = sum; q = mean/S; cumsum;
//    cdf = min(int(c*2048), 2047).
__global__ void scanD_kernel(const double* __restrict__ partD, int* __restrict__ cdf) {
  __shared__ double part[256];
  __shared__ double base[256];
  __shared__ double Ss;
  int tid = threadIdx.x;
  double loc[16];
  double s = 0.0;
#pragma unroll
  for (int i = 0; i < 16; ++i) {
    int tf = tid * 16 + i;
    double m = 0.0;
#pragma unroll
    for (int ch = 0; ch < 8; ++ch) m += partD[ch * 4096 + tf];  // in c-order
    loc[i] = m / 512.0;
    s += loc[i];
  }
  part[tid] = s;
  __syncthreads();
  if (tid == 0) {
    double t = 0.0;
    for (int i = 0; i < 256; ++i) t += part[i];
    Ss = t;
  }
  __syncthreads();
  double S = Ss;
  s = 0.0;
#pragma unroll
  for (int i = 0; i < 16; ++i) { loc[i] = loc[i] / S; s += loc[i]; }
  part[tid] = s;
  __syncthreads();
  if (tid == 0) {
    double c = 0.0;
    for (int i = 0; i < 256; ++i) { base[i] = c; c += part[i]; }
  }
  __syncthreads();
  double c = base[tid];
#pragma unroll
  for (int i = 0; i < 16; ++i) {
    c += loc[i];
    int iv = (int)(c * 2048.0);                      // trunc = astype(int32)
    cdf[tid * 16 + i] = iv < 2047 ? iv : 2047;
  }
}

// ---------------------------------------------------------------------------
// 3. idx[target] = first argmin_j |cdf[j]-target|
__global__ void argmin_kernel(const int* __restrict__ cdf, int* __restrict__ idx) {
  __shared__ int sd[256], sj[256];
  int target = blockIdx.x;                            // 2048 blocks
  int tid = threadIdx.x;
  int best = 0x7fffffff, bj = 0x7fffffff;
  for (int j = tid; j < 4096; j += 256) {
    int d = cdf[j] - target; d = d < 0 ? -d : d;
    if (d < best) { best = d; bj = j; }               // strict < keeps first
  }
  sd[tid] = best; sj[tid] = bj;
  __syncthreads();
  for (int s = 128; s > 0; s >>= 1) {
    if (tid < s) {
      if (sd[tid+s] < sd[tid] || (sd[tid+s] == sd[tid] && sj[tid+s] < sj[tid])) {
        sd[tid] = sd[tid+s]; sj[tid] = sj[tid+s];
      }
    }
    __syncthreads();
  }
  if (tid == 0) idx[target] = sj[0];
}

// ---------------------------------------------------------------------------
// 4. gather transposed: X3T[b][t][c] = bf16(frame[b][c][idx[t]]), c in [0,512)
__global__ void gatherT_kernel(const float* __restrict__ frame, const int* __restrict__ idx,
                               u16* __restrict__ X3T) {
  __shared__ u16 tile[64][65];
  __shared__ int sidx[64];
  int cb = blockIdx.x * 64, t0 = blockIdx.y * 64, b = blockIdx.z;
  int tid = threadIdx.x;
  if (tid < 64) {
    int it = idx[t0 + tid];
    sidx[tid] = it < 0 ? 0 : (it > 4095 ? 4095 : it);
  }
  __syncthreads();
  const float* fb = frame + (size_t)b * 512 * 4096;
  for (int i = tid; i < 4096; i += 256) {
    int r = i >> 6, tt = i & 63;        // r = c-local, tt = t-local
    tile[tt][r] = f2bf(fb[(size_t)(cb + r) * 4096 + sidx[tt]]);
  }
  __syncthreads();
  u16* xb = X3T + (size_t)b * 2048 * 2048;
  for (int i = tid; i < 4096; i += 256) {
    int r = i >> 6, cc = i & 63;        // r = t-local, cc = c-local
    xb[(size_t)(t0 + r) * 2048 + cb + cc] = tile[r][cc];
  }
}

// ---------------------------------------------------------------------------
// 5. feature (B,512c,2048t) fp32 -> featT (B,2048t,512c) bf16, LDS 64x64
__global__ void transposeCT_kernel(const float* __restrict__ X, u16* __restrict__ XT) {
  __shared__ u16 tile[64][65];
  int cb = blockIdx.x * 64, t0 = blockIdx.y * 64, b = blockIdx.z;
  int tid = threadIdx.x;
  const float* xb = X + (size_t)b * 512 * 2048;
  for (int i = tid; i < 4096; i += 256) {
    int r = i >> 6, tt = i & 63;        // coalesced along t
    tile[tt][r] = f2bf(xb[(size_t)(cb + r) * 2048 + t0 + tt]);
  }
  __syncthreads();
  u16* xtb = XT + (size_t)b * 2048 * 512;
  for (int i = tid; i < 4096; i += 256) {
    int r = i >> 6, cc = i & 63;
    xtb[(size_t)(t0 + r) * 512 + cb + cc] = tile[r][cc];
  }
}

// ---------------------------------------------------------------------------
// 6. W1 (262144) ++ W2 (524288) fp32 -> W12b bf16 (stacked rows, K=512)
__global__ void convW12_kernel(const float* __restrict__ W1, const float* __restrict__ W2,
                               u16* __restrict__ dst) {
  int i = blockIdx.x * 256 + threadIdx.x;            // 786432
  dst[i] = f2bf(i < 262144 ? W1[i] : W2[i - 262144]);
}
__global__ void convW_kernel(const float* __restrict__ src, u16* __restrict__ dst, int n) {
  int i = blockIdx.x * 256 + threadIdx.x;
  if (i < n) dst[i] = f2bf(src[i]);
}

// ---------------------------------------------------------------------------
// 7a. fused GEMM1+2: Y12[b][m][n] = sum_k W12[m][k]*featT[b][n][k] + bias(m)
//     M=1536, N=2048, K=512. 64x128 tile, 2 waves, dbuf prefetch.
__global__ __launch_bounds__(128) void gemm12_kernel(
    const u16* __restrict__ A, const u16* __restrict__ Bt,
    const float* __restrict__ b1, const float* __restrict__ b2,
    float* __restrict__ Y)
{
  const int K = 512;
  __shared__ short As[2][2048];   // [buf][64 m][32 k]
  __shared__ short Bs[2][4096];   // [buf][128 n][32 k]
  const int tid = threadIdx.x;
  const int lane = tid & 63;
  const int w = tid >> 6;
  const int nt = blockIdx.x, mt = blockIdx.y, bb = blockIdx.z;
  const u16* Ab = A + (size_t)mt * 64 * K;
  const u16* Bb = Bt + ((size_t)bb * 2048 + (size_t)nt * 128) * K;
  const int lm = lane & 15, lq = lane >> 4;
  f32x4 acc[4][4] = {};

  auto stage = [&](int buf, int kt) {
#pragma unroll
    for (int p = 0; p < 2; ++p) {
      int chunk = tid + 128 * p;
      int row = chunk >> 2, ko = (chunk & 3) << 3;
      gld16(Ab + (size_t)row * K + kt + ko, (char*)As[buf] + chunk * 16);
    }
#pragma unroll
    for (int p = 0; p < 4; ++p) {
      int chunk = tid + 128 * p;
      int row = chunk >> 2, ko = (chunk & 3) << 3;
      gld16(Bb + (size_t)row * K + kt + ko, (char*)Bs[buf] + chunk * 16);
    }
  };

  stage(0, 0);
  for (int s = 0; s < 16; ++s) {
    int cur = s & 1;
    __syncthreads();
    if (s + 1 < 16) stage(cur ^ 1, (s + 1) << 5);
    short8 af[4], bfv[4];
#pragma unroll
    for (int i = 0; i < 4; ++i)
      af[i] = *(const short8*)(As[cur] + ((i * 16 + lm) * 32 + lq * 8));
#pragma unroll
    for (int j = 0; j < 4; ++j)
      bfv[j] = *(const short8*)(Bs[cur] + ((w * 64 + j * 16 + lm) * 32 + lq * 8));
#pragma unroll
    for (int i = 0; i < 4; ++i)
#pragma unroll
      for (int j = 0; j < 4; ++j)
        acc[i][j] = __builtin_amdgcn_mfma_f32_16x16x32_bf16(af[i], bfv[j], acc[i][j], 0, 0, 0);
  }
#pragma unroll
  for (int i = 0; i < 4; ++i) {
    int mbase = mt * 64 + i * 16 + lq * 4;
#pragma unroll
    for (int e = 0; e < 4; ++e) {
      int m = mbase + e;
      float bv = m < 512 ? b1[m] : b2[m - 512];
      float* yp = Y + ((size_t)bb * 1536 + m) * 2048 + nt * 128 + w * 64 + lm;
#pragma unroll
      for (int j = 0; j < 4; ++j)
        yp[j * 16] = acc[i][j][e] + bv;
    }
  }
}

// ---------------------------------------------------------------------------
// 7b. GEMM3 split-K x2: partial[ks][b][m][n] = sum_{k in half ks} W3[m][k]*X3T[b][n][k]
//     (+bias if ks==0). M=512, N=2048, K=2048. grid.z = b*2+ks.
__global__ __launch_bounds__(128) void gemm3s_kernel(
    const u16* __restrict__ A, const u16* __restrict__ Bt,
    const float* __restrict__ bias, float* __restrict__ Yp)
{
  const int K = 2048;
  __shared__ short As[2][2048];
  __shared__ short Bs[2][4096];
  const int tid = threadIdx.x;
  const int lane = tid & 63;
  const int w = tid >> 6;
  const int nt = blockIdx.x, mt = blockIdx.y;
  const int bb = blockIdx.z >> 1, ks = blockIdx.z & 1;
  const u16* Ab = A + (size_t)mt * 64 * K + ks * 1024;
  const u16* Bb = Bt + ((size_t)bb * 2048 + (size_t)nt * 128) * K + ks * 1024;
  const int lm = lane & 15, lq = lane >> 4;
  f32x4 acc[4][4] = {};

  auto stage = [&](int buf, int kt) {
#pragma unroll
    for (int p = 0; p < 2; ++p) {
      int chunk = tid + 128 * p;
      int row = chunk >> 2, ko = (chunk & 3) << 3;
      gld16(Ab + (size_t)row * K + kt + ko, (char*)As[buf] + chunk * 16);
    }
#pragma unroll
    for (int p = 0; p < 4; ++p) {
      int chunk = tid + 128 * p;
      int row = chunk >> 2, ko = (chunk & 3) << 3;
      gld16(Bb + (size_t)row * K + kt + ko, (char*)Bs[buf] + chunk * 16);
    }
  };

  stage(0, 0);
  for (int s = 0; s < 32; ++s) {
    int cur = s & 1;
    __syncthreads();
    if (s + 1 < 32) stage(cur ^ 1, (s + 1) << 5);
    short8 af[4], bfv[4];
#pragma unroll
    for (int i = 0; i < 4; ++i)
      af[i] = *(const short8*)(As[cur] + ((i * 16 + lm) * 32 + lq * 8));
#pragma unroll
    for (int j = 0; j < 4; ++j)
      bfv[j] = *(const short8*)(Bs[cur] + ((w * 64 + j * 16 + lm) * 32 + lq * 8));
#pragma unroll
    for (int i = 0; i < 4; ++i)
#pragma unroll
      for (int j = 0; j < 4; ++j)
        acc[i][j] = __builtin_amdgcn_mfma_f32_16x16x32_bf16(af[i], bfv[j], acc[i][j], 0, 0, 0);
  }
#pragma unroll
  for (int i = 0; i < 4; ++i) {
    int mbase = mt * 64 + i * 16 + lq * 4;
#pragma unroll
    for (int e = 0; e < 4; ++e) {
      int m = mbase + e;
      float bv = ks ? 0.f : bias[m];
      float* yp = Yp + ((size_t)(ks * 4 + bb) * 512 + m) * 2048 + nt * 128 + w * 64 + lm;
#pragma unroll
      for (int j = 0; j < 4; ++j)
        yp[j * 16] = acc[i][j][e] + bv;
    }
  }
}

// ---------------------------------------------------------------------------
// 8a. merged GN stats stage-1 for Y12: gy<32 -> Y1 groups (cpg16), else Y2 (cpg32)
__global__ void statsP12_kernel(const float* __restrict__ Y12,
                                float* __restrict__ raw1, float* __restrict__ raw2) {
  int chunk = blockIdx.x, gy = blockIdx.y, b = blockIdx.z, tid = threadIdx.x;
  int cpg, chBase, g; float* raw;
  if (gy < 32) { if (chunk >= 8) return; cpg = 16; chBase = 0;   g = gy;      raw = raw1; }
  else         {                         cpg = 32; chBase = 512; g = gy - 32; raw = raw2; }
  const float* base = Y12 + ((size_t)b * 1536 + chBase + g * cpg) * 2048 + (size_t)chunk * 4096;
  float s = 0.f, ss = 0.f;
#pragma unroll
  for (int i = 0; i < 16; ++i) { float v = base[tid + 256 * i]; s += v; ss += v * v; }
  __shared__ float s1[256], s2[256];
  s1[tid] = s; s2[tid] = ss;
  __syncthreads();
  for (int st = 128; st > 0; st >>= 1) {
    if (tid < st) { s1[tid] += s1[tid + st]; s2[tid] += s2[tid + st]; }
    __syncthreads();
  }
  if (tid == 0) {
    atomicAdd(&raw[(b * 32 + g) * 2],     s1[0]);
    atomicAdd(&raw[(b * 32 + g) * 2 + 1], s2[0]);
  }
}

// 8b. stage-1 for split-K Y3: reads partial pair (second at +4194304 floats)
__global__ void stats3p_kernel(const float* __restrict__ Yp, float* __restrict__ raw) {
  int chunk = blockIdx.x, g = blockIdx.y, b = blockIdx.z, tid = threadIdx.x;
  const float* base = Yp + ((size_t)b * 512 + g * 16) * 2048 + (size_t)chunk * 4096;
  float s = 0.f, ss = 0.f;
#pragma unroll
  for (int i = 0; i < 16; ++i) {
    int o = tid + 256 * i;
    float v = base[o] + base[o + 4194304];
    s += v; ss += v * v;
  }
  __shared__ float s1[256], s2[256];
  s1[tid] = s; s2[tid] = ss;
  __syncthreads();
  for (int st = 128; st > 0; st >>= 1) {
    if (tid < st) { s1[tid] += s1[tid + st]; s2[tid] += s2[tid + st]; }
    __syncthreads();
  }
  if (tid == 0) {
    atomicAdd(&raw[(b * 32 + g) * 2],     s1[0]);
    atomicAdd(&raw[(b * 32 + g) * 2 + 1], s2[0]);
  }
}

// 8c. finalize mu, rs. 256 threads: i<128 -> st1 (n=32768); else st2 (n=65536)
__global__ void statsFin12_kernel(const float* __restrict__ raw1, const float* __restrict__ raw2,
                                  float* __restrict__ st1, float* __restrict__ st2) {
  int i = threadIdx.x;
  const float* raw = i < 128 ? raw1 : raw2;
  float* st = i < 128 ? st1 : st2;
  int j = i & 127;
  float n = i < 128 ? 32768.f : 65536.f;
  float mu = raw[j * 2] / n;
  float var = raw[j * 2 + 1] / n - mu * mu;
  st[j * 2] = mu;
  st[j * 2 + 1] = 1.0f / sqrtf(var + 1e-5f);
}
__global__ void statsFin_kernel(const float* __restrict__ raw, float* __restrict__ stats,
                                float n) {
  int i = threadIdx.x;                                // 128
  float mu = raw[i * 2] / n;
  float var = raw[i * 2 + 1] / n - mu * mu;
  stats[i * 2] = mu;
  stats[i * 2 + 1] = 1.0f / sqrtf(var + 1e-5f);
}

// ---------------------------------------------------------------------------
// 9. GN+ReLU from Y12 rows [chBase, chBase+C); bf16 transposed into
//    X3T[b][t][colBase+c]; optional fp32 row-major copy to featOut.
__global__ void normT_kernel(const float* __restrict__ Y, const float* __restrict__ stats,
                             const float* __restrict__ gamma, const float* __restrict__ beta,
                             int rowsB, int chBase, int C, int gShift,
                             u16* __restrict__ X3T, int colBase,
                             float* __restrict__ featOut) {
  __shared__ u16 tile[64][65];           // [t_local][c_local]
  int b = blockIdx.z, c0 = blockIdx.y * 64, t0 = blockIdx.x * 64;
  const float* yb = Y + ((size_t)b * rowsB + chBase) * 2048;
  for (int i = threadIdx.x; i < 4096; i += 256) {
    int r = i >> 6, cc = i & 63;         // r: channel-local, cc: t-local
    int ch = c0 + r;
    int gI = (b * 32 + (ch >> gShift)) * 2;
    float mu = stats[gI], rs = stats[gI + 1];
    float v = yb[(size_t)ch * 2048 + t0 + cc];
    float o = relu((v - mu) * rs * gamma[ch] + beta[ch]);
    tile[cc][r] = f2bf(o);
    if (featOut) featOut[((size_t)b * C + ch) * 2048 + t0 + cc] = o;
  }
  __syncthreads();
  for (int i = threadIdx.x; i < 4096; i += 256) {
    int r = i >> 6, cc = i & 63;         // r: t-local, cc: c-local
    X3T[((size_t)b * 2048 + t0 + r) * 2048 + colBase + c0 + cc] = tile[r][cc];
  }
}

// ---------------------------------------------------------------------------
// 10. GN+ReLU for split-K Y3 partial pair -> fp32 mixed output
__global__ void norm3_kernel(const float* __restrict__ Yp, const float* __restrict__ stats,
                             const float* __restrict__ gamma, const float* __restrict__ beta,
                             float* __restrict__ out) {
  int i = blockIdx.x * 256 + threadIdx.x;            // 4,194,304 total
  int b = i >> 20;
  int ch = (i >> 11) & 511;
  int gI = (b * 32 + (ch >> 4)) * 2;
  float mu = stats[gI], rs = stats[gI + 1];
  float v = Yp[i] + Yp[i + 4194304];
  out[i] = relu((v - mu) * rs * gamma[ch] + beta[ch]);
}

// ---------------------------------------------------------------------------
extern "C" void kernel_launch(void* const* d_in, const int* in_sizes, int n_in,
                              void* d_out, int out_size, void* d_ws, size_t ws_size,
                              hipStream_t stream) {
  const float* feature = (const float*)d_in[0];
  const float* frame   = (const float*)d_in[1];
  const float* W1 = (const float*)d_in[2];
  const float* b1 = (const float*)d_in[3];
  const float* g1 = (const float*)d_in[4];
  const float* be1 = (const float*)d_in[5];
  const float* W2 = (const float*)d_in[6];
  const float* b2 = (const float*)d_in[7];
  const float* g2 = (const float*)d_in[8];
  const float* be2 = (const float*)d_in[9];
  const float* W3 = (const float*)d_in[10];
  const float* b3 = (const float*)d_in[11];
  const float* g3 = (const float*)d_in[12];
  const float* be3 = (const float*)d_in[13];

  char* ws = (char*)d_ws;
  // Layout / stream-ordered aliasing:
  //   X3T   [0, 32MiB)            bf16 (B,2048t,2048c)
  //   Y12f  [32MiB, 80MiB)        f32 (B,1536,2048) = GEMM1+2 output
  //   Y3p   [32MiB, 64MiB)        f32 split-K partial pair (after normT1/2)
  //   W3b   [64MiB, 66MiB)        bf16, written after normT2 (Y12 dead)
  //   partD [48MiB, +256KiB)      f64, dead before gemm12 writes Y12
  //   featT [80MiB, 88MiB)        bf16 (B,2048,512)
  //   W12b  [88MiB, +1.5MiB)      bf16 stacked W1;W2
  //   small tail after W12b
  u16*    X3T   = (u16*)(ws + 0);
  float*  Y12f  = (float*)(ws + 33554432);
  float*  Y3p   = (float*)(ws + 33554432);
  u16*    W3b   = (u16*)(ws + 67108864);
  double* partD = (double*)(ws + 50331648);
  u16*    featT = (u16*)(ws + 83886080);
  u16*    W12b  = (u16*)(ws + 92274688);
  int*    cdf   = (int*)(ws + 93847552);
  int*    idx   = (int*)(ws + 93863936);
  float*  raw1  = (float*)(ws + 93872128);
  float*  raw2  = (float*)(ws + 93873152);
  float*  raw3  = (float*)(ws + 93874176);
  float*  st1   = (float*)(ws + 93875200);
  float*  st2   = (float*)(ws + 93876224);
  float*  st3   = (float*)(ws + 93877248);

  float* outMixed = (float*)d_out;                       // (B,512,2048) fp32
  float* outFeat  = outMixed + (size_t)4 * 512 * 2048;   // (B,1024,2048) fp32

  hipMemsetAsync(raw1, 0, 3 * 1024, stream);             // raw1/raw2/raw3

  colmean_part_kernel<<<dim3(16, 8), 256, 0, stream>>>(frame, partD);
  scanD_kernel<<<1, 256, 0, stream>>>(partD, cdf);
  argmin_kernel<<<2048, 256, 0, stream>>>(cdf, idx);
  gatherT_kernel<<<dim3(8, 32, 4), 256, 0, stream>>>(frame, idx, X3T);
  transposeCT_kernel<<<dim3(8, 32, 4), 256, 0, stream>>>(feature, featT);

  convW12_kernel<<<3072, 256, 0, stream>>>(W1, W2, W12b);
  gemm12_kernel<<<dim3(16, 24, 4), 128, 0, stream>>>(W12b, featT, b1, b2, Y12f);
  statsP12_kernel<<<dim3(16, 64, 4), 256, 0, stream>>>(Y12f, raw1, raw2);
  statsFin12_kernel<<<1, 256, 0, stream>>>(raw1, raw2, st1, st2);
  normT_kernel<<<dim3(32, 8, 4), 256, 0, stream>>>(Y12f, st1, g1, be1, 1536, 0, 512, 4,
                                                   X3T, 1536, (float*)nullptr);
  normT_kernel<<<dim3(32, 16, 4), 256, 0, stream>>>(Y12f, st2, g2, be2, 1536, 512, 1024, 5,
                                                    X3T, 512, outFeat);
  convW_kernel<<<4096, 256, 0, stream>>>(W3, W3b, 1048576);
  gemm3s_kernel<<<dim3(16, 8, 8), 128, 0, stream>>>(W3b, X3T, b3, Y3p);
  stats3p_kernel<<<dim3(8, 32, 4), 256, 0, stream>>>(Y3p, raw3);
  statsFin_kernel<<<1, 128, 0, stream>>>(raw3, st3, 32768.f);
  norm3_kernel<<<16384, 256, 0, stream>>>(Y3p, st3, g3, be3, outMixed);
}